// Round 8
// baseline (299.117 us; speedup 1.0000x reference)
//
#include <hip/hip_runtime.h>

typedef float f32x4 __attribute__((ext_vector_type(4)));
typedef _Float16 h16x8 __attribute__((ext_vector_type(8)));

#define LGKM0 asm volatile("s_waitcnt lgkmcnt(0)" ::: "memory")

// ---------------------------------------------------------------------------
// Fragment-native layout: buffer = chunks of 64 lanes x 16B. Chunk (rb, kc)
// holds rows rb*16..+15, k kc*32..+31; lane = (row&15) + 16*((k>>3)&3),
// 8 f16 per lane. This is exactly the gfx950 mfma_16x16x32 A/B operand
// mapping (verified by R1-R7 passing kernels). chunk index = rb*CS + kc.
// ---------------------------------------------------------------------------

// cast x f32 [8192][1024] -> xhN native (rb 0..511, kc 0..31, CS=32)
__global__ __launch_bounds__(256) void cast_xn(const float* __restrict__ x,
                                               h16x8* __restrict__ xhN) {
  const int w = blockIdx.x * 4 + (threadIdx.x >> 6);  // chunk id = rb*32+kc
  const int lane = threadIdx.x & 63;
  const int l15 = lane & 15, lg = lane >> 4;
  const int rb = w >> 5, kc = w & 31;
  const float* src = x + (long)(rb * 16 + l15) * 1024 + kc * 32 + lg * 8;
  f32x4 a = *(const f32x4*)src;
  f32x4 b = *(const f32x4*)(src + 4);
  h16x8 h;
  h[0] = (_Float16)a[0]; h[1] = (_Float16)a[1];
  h[2] = (_Float16)a[2]; h[3] = (_Float16)a[3];
  h[4] = (_Float16)b[0]; h[5] = (_Float16)b[1];
  h[6] = (_Float16)b[2]; h[7] = (_Float16)b[3];
  xhN[(long)w * 64 + lane] = h;
}

// W f32 [1024 in][Nd out] -> WpN native over (row=out n, k=in), CS=32,
// chunk = (nofs + nb)*32 + kc. Covers q12|k12|v into one 5120-row buffer.
__global__ __launch_bounds__(256) void tcwn(const float* __restrict__ W,
                                            h16x8* __restrict__ WpN,
                                            int Nd, int nofs, float scale) {
  const int w = blockIdx.x * 4 + (threadIdx.x >> 6);
  const int lane = threadIdx.x & 63;
  const int l15 = lane & 15, lg = lane >> 4;
  const int nb = w >> 5, kc = w & 31;
  const float* src = W + (long)(kc * 32 + lg * 8) * Nd + nb * 16 + l15;
  h16x8 h;
#pragma unroll
  for (int i = 0; i < 8; ++i) h[i] = (_Float16)(src[(long)i * Nd] * scale);
  WpN[((long)(nofs + nb) * 32 + kc) * 64 + lane] = h;
}

// ---------------------------------------------------------------------------
// lambda_full = exp(sum lq1*lk1) - exp(sum lq2*lk2) + 0.8
__global__ __launch_bounds__(1024) void lambda_k(const float* __restrict__ lq1,
                                                 const float* __restrict__ lk1,
                                                 const float* __restrict__ lq2,
                                                 const float* __restrict__ lk2,
                                                 float* __restrict__ lam) {
  __shared__ float sh1[16], sh2[16];
  const int t = threadIdx.x;
  float p1 = lq1[t] * lk1[t];
  float p2 = lq2[t] * lk2[t];
#pragma unroll
  for (int off = 1; off < 64; off <<= 1) {
    p1 += __shfl_xor(p1, off);
    p2 += __shfl_xor(p2, off);
  }
  if ((t & 63) == 0) { sh1[t >> 6] = p1; sh2[t >> 6] = p2; }
  __syncthreads();
  if (t == 0) {
    float s1 = 0.f, s2 = 0.f;
    for (int i = 0; i < 16; ++i) { s1 += sh1[i]; s2 += sh2[i]; }
    lam[0] = __expf(s1) - __expf(s2) + 0.8f;
  }
}

// ---------------------------------------------------------------------------
// Fragment-direct GEMM: no LDS for operands, no barriers. Per wave 128x64
// tile: 8 A-frags x 4 B-frags per K-step (K=32), acc[8][4] f32x4. Double-
// buffered register pipeline (named E/O buffers, rule-20-safe). Operands are
// frag-native; every load is a coalesced 1KB global_load_dwordx4.
// MODE 0: qkv (A=xhN CS32, B=WpN CS32, NS=32; epi: nt<64 -> q/k native to
//         outN (CS 128); nt>=64 -> v^T-native to vtN).
// MODE 1: S1+S2 (A,B=qkvN CS128, kcoff att*32 / 64+att*32, NS=32; epi:
//         row-linear f16 to Sbuf plane (att*4+z)).
// MODE 2: PV (A=diffN CS64, B=vtN CS64, NS=64; epi row-linear to opre).
// Deliberate overshoot loads (kc=NS..NS+1) land in adjacent ws regions and
// are never consumed. Epilogue uses wave-private LDS scratch (no barrier).
template <int MODE>
__global__ __launch_bounds__(256, 2) void gemmf(
    const h16x8* __restrict__ A0, const h16x8* __restrict__ B0,
    _Float16* __restrict__ out0, h16x8* __restrict__ outN,
    h16x8* __restrict__ vtN) {
  constexpr int NS = (MODE == 2) ? 64 : 32;
  constexpr int CS = (MODE == 0) ? 32 : (MODE == 1) ? 128 : 64;

  // bijective XCD swizzle (grids are multiples of 8)
  const int nwg = gridDim.x, orig = blockIdx.x;
  const int wgid = (orig & 7) * (nwg >> 3) + (orig >> 3);

  int bm, bn, z = 0, att = 0;
  if constexpr (MODE == 0) { bm = wgid & 31; bn = wgid >> 5; }           // 32x40
  else if constexpr (MODE == 1) {                                        // 8 x (8x16)
    const int b = wgid >> 7, r = wgid & 127;
    bm = r & 7; bn = r >> 3; att = b >> 2; z = b & 3;
  } else { bm = wgid & 31; bn = wgid >> 5; }                             // 32x8

  const int t = threadIdx.x, lane = t & 63, wv = t >> 6;
  const int wm = wv >> 1, wn = wv & 1;
  const int l15 = lane & 15, lg = lane >> 4;
  const int mt = bm * 2 + wm, nt = bn * 2 + wn;

  long Ac, Bc;  // base chunk indices
  if constexpr (MODE == 0) {
    Ac = (long)mt * 8 * 32;
    Bc = (long)nt * 4 * 32;
  } else if constexpr (MODE == 1) {
    Ac = ((long)z * 128 + mt * 8) * 128 + att * 32;        // q1/q2
    Bc = ((long)z * 128 + nt * 4) * 128 + 64 + att * 32;   // k1/k2
  } else {
    const int zz = mt >> 4;
    Ac = ((long)zz * 128 + (mt & 15) * 8) * 64;
    Bc = ((long)zz * 64 + nt * 4) * 64;
  }
  const h16x8* Aw = A0 + Ac * 64 + lane;
  const h16x8* Bw = B0 + Bc * 64 + lane;

  f32x4 acc[8][4] = {};
  h16x8 aE[8], aO[8], bE[4], bO[4];

  auto lda = [&](h16x8(&d)[8], int kc) {
#pragma unroll
    for (int m = 0; m < 8; ++m) d[m] = Aw[((long)m * CS + kc) * 64];
  };
  auto ldb = [&](h16x8(&d)[4], int kc) {
#pragma unroll
    for (int n = 0; n < 4; ++n) d[n] = Bw[((long)n * CS + kc) * 64];
  };
  auto step = [&](h16x8(&a)[8], h16x8(&b)[4]) {
#pragma unroll
    for (int m = 0; m < 8; ++m)
#pragma unroll
      for (int n = 0; n < 4; ++n)
        acc[m][n] = __builtin_amdgcn_mfma_f32_16x16x32_f16(a[m], b[n], acc[m][n], 0, 0, 0);
  };

  lda(aE, 0); ldb(bE, 0);
  lda(aO, 1); ldb(bO, 1);
#pragma unroll 1
  for (int kc = 0; kc < NS; kc += 2) {
    step(aE, bE);
    lda(aE, kc + 2); ldb(bE, kc + 2);   // prefetch; latency hides under step(O)
    step(aO, bO);
    lda(aO, kc + 3); ldb(bO, kc + 3);
  }

  // ---------------- epilogue via wave-private LDS scratch -----------------
  __shared__ float smem[4][2048];   // 8KB per wave
  float* sw = smem[wv];

  if constexpr (MODE == 0) {
    if (nt < 64) {
      // q|k columns -> frag-native for the S-GEMM (CS 128)
#pragma unroll
      for (int m = 0; m < 8; ++m) {
        LGKM0;
#pragma unroll
        for (int n = 0; n < 4; ++n)   // LDS[col][row] f32
          *(f32x4*)(sw + (n * 16 + l15) * 16 + lg * 4) = acc[m][n];
        LGKM0;
#pragma unroll
        for (int h = 0; h < 2; ++h) {
          h16x8 hv;
#pragma unroll
          for (int i = 0; i < 8; ++i)
            hv[i] = (_Float16)sw[(h * 32 + lg * 8 + i) * 16 + l15];
          outN[(((long)mt * 8 + m) * 128 + nt * 2 + h) * 64 + lane] = hv;
        }
      }
    } else {
      // v columns -> v^T-native (row = d, k = key) for PV's B operand
      const int ntv = nt - 64;
      const int zz = mt >> 4, mtl = mt & 15;
      h16x8* vz = vtN + (long)zz * 4096 * 64;
#pragma unroll
      for (int p = 0; p < 4; ++p) {   // frag pairs: 32 keys
        LGKM0;
#pragma unroll
        for (int qq = 0; qq < 2; ++qq)
#pragma unroll
          for (int n = 0; n < 4; ++n)  // LDS[d 64][key 32] f32
            *(f32x4*)(sw + (n * 16 + l15) * 32 + qq * 16 + lg * 4) = acc[p * 2 + qq][n];
        LGKM0;
#pragma unroll
        for (int d = 0; d < 4; ++d) {
          f32x4 lo = *(const f32x4*)(sw + (d * 16 + l15) * 32 + lg * 8);
          f32x4 hi = *(const f32x4*)(sw + (d * 16 + l15) * 32 + lg * 8 + 4);
          h16x8 hv;
          hv[0] = (_Float16)lo[0]; hv[1] = (_Float16)lo[1];
          hv[2] = (_Float16)lo[2]; hv[3] = (_Float16)lo[3];
          hv[4] = (_Float16)hi[0]; hv[5] = (_Float16)hi[1];
          hv[6] = (_Float16)hi[2]; hv[7] = (_Float16)hi[3];
          vz[(((long)ntv * 4 + d) * 64 + mtl * 4 + p) * 64 + lane] = hv;
        }
      }
    }
  } else {
    _Float16* orow;
    long ldc;
    if constexpr (MODE == 1) {
      orow = out0 + ((long)att * 4 + z) * 2048 * 2048 + (long)mt * 128 * 2048 + nt * 64;
      ldc = 2048;
    } else {
      orow = out0 + (long)mt * 128 * 1024 + nt * 64;
      ldc = 1024;
    }
#pragma unroll
    for (int m = 0; m < 8; ++m) {
      LGKM0;
#pragma unroll
      for (int n = 0; n < 4; ++n)
        *(f32x4*)(sw + (n * 16 + l15) * 16 + lg * 4) = acc[m][n];
      LGKM0;
#pragma unroll
      for (int h = 0; h < 2; ++h) {
        const int rl = h * 8 + (lane >> 3), c8 = lane & 7;
        h16x8 hv;
#pragma unroll
        for (int i = 0; i < 8; ++i)
          hv[i] = (_Float16)sw[(c8 * 8 + i) * 16 + rl];
        *(h16x8*)(orow + (long)(m * 16 + rl) * ldc + c8 * 8) = hv;
      }
    }
  }
}

// ---------------------------------------------------------------------------
// diff = softmax(S1) - lam*softmax(S2); reads row-linear S, writes diff in
// PV's frag-native layout. Block = 16 rows (one rb); 4 waves x 4 rows.
__global__ __launch_bounds__(256) void softmax_diffn(
    const _Float16* __restrict__ Sb, h16x8* __restrict__ diffN,
    const float* __restrict__ lamp) {
  __shared__ _Float16 dl[16][2056];   // pad 8 f16: conflict-light readback
  const int rb = blockIdx.x;          // 0..511
  const int z = rb >> 7, rbl = rb & 127;
  const int t = threadIdx.x, lane = t & 63, wv = t >> 6;
  const int l15 = lane & 15, lg = lane >> 4;
  const float lam = *lamp;
  const _Float16* S1r = Sb + (long)z * 2048 * 2048 + (long)rbl * 16 * 2048;
  const _Float16* S2r = S1r + (long)4 * 2048 * 2048;

  for (int qi = 0; qi < 4; ++qi) {
    const int r = wv * 4 + qi;
    const _Float16* s1 = S1r + (long)r * 2048;
    const _Float16* s2 = S2r + (long)r * 2048;
    float v1[32], v2[32];
    float m1 = -3e38f, m2 = -3e38f;
#pragma unroll
    for (int j = 0; j < 4; ++j) {
      h16x8 a = ((const h16x8*)s1)[j * 64 + lane];
      h16x8 b = ((const h16x8*)s2)[j * 64 + lane];
#pragma unroll
      for (int q = 0; q < 8; ++q) {
        v1[j * 8 + q] = (float)a[q]; v2[j * 8 + q] = (float)b[q];
        m1 = fmaxf(m1, v1[j * 8 + q]); m2 = fmaxf(m2, v2[j * 8 + q]);
      }
    }
#pragma unroll
    for (int off = 1; off < 64; off <<= 1) {
      m1 = fmaxf(m1, __shfl_xor(m1, off));
      m2 = fmaxf(m2, __shfl_xor(m2, off));
    }
    float l1 = 0.f, l2 = 0.f;
#pragma unroll
    for (int e = 0; e < 32; ++e) {
      v1[e] = __expf(v1[e] - m1); l1 += v1[e];
      v2[e] = __expf(v2[e] - m2); l2 += v2[e];
    }
#pragma unroll
    for (int off = 1; off < 64; off <<= 1) {
      l1 += __shfl_xor(l1, off);
      l2 += __shfl_xor(l2, off);
    }
    const float r1 = 1.f / l1, r2 = lam / l2;
#pragma unroll
    for (int j = 0; j < 4; ++j) {
      h16x8 h;
#pragma unroll
      for (int q = 0; q < 8; ++q)
        h[q] = (_Float16)(v1[j * 8 + q] * r1 - v2[j * 8 + q] * r2);
      *(h16x8*)(&dl[r][(j * 64 + lane) * 8]) = h;
    }
  }
  __syncthreads();
  h16x8* dz = diffN + (long)z * 8192 * 64;
#pragma unroll
  for (int cc = 0; cc < 16; ++cc) {
    const int kc = wv * 16 + cc;
    h16x8 hv = *(const h16x8*)(&dl[l15][kc * 32 + lg * 8]);
    dz[((long)rbl * 64 + kc) * 64 + lane] = hv;
  }
}

// ---------------------------------------------------------------------------
// one wave per row: out = O / sqrt(mean(O^2) + eps) * 0.2, f16 in, f32 out
__global__ __launch_bounds__(256) void rmsnorm(const _Float16* __restrict__ O,
                                               float* __restrict__ out) {
  const long row = (long)blockIdx.x * 4 + (threadIdx.x >> 6);
  const int lane = threadIdx.x & 63;
  const _Float16* o = O + row * 1024;
  h16x8 a = ((const h16x8*)o)[lane];
  h16x8 b = ((const h16x8*)o)[64 + lane];
  float xa[8], xb[8];
  float ss = 0.f;
#pragma unroll
  for (int q = 0; q < 8; ++q) {
    xa[q] = (float)a[q]; xb[q] = (float)b[q];
    ss += xa[q] * xa[q] + xb[q] * xb[q];
  }
#pragma unroll
  for (int off = 1; off < 64; off <<= 1) ss += __shfl_xor(ss, off);
  const float s = 0.2f * rsqrtf(ss * (1.f / 1024.f) + 1e-5f);
  float* po = out + row * 1024;
  f32x4 r;
#pragma unroll
  for (int q = 0; q < 4; ++q) r[q] = xa[q] * s;
  *(f32x4*)(po + lane * 8) = r;
#pragma unroll
  for (int q = 0; q < 4; ++q) r[q] = xa[4 + q] * s;
  *(f32x4*)(po + lane * 8 + 4) = r;
#pragma unroll
  for (int q = 0; q < 4; ++q) r[q] = xb[q] * s;
  *(f32x4*)(po + 512 + lane * 8) = r;
#pragma unroll
  for (int q = 0; q < 4; ++q) r[q] = xb[4 + q] * s;
  *(f32x4*)(po + 512 + lane * 8 + 4) = r;
}

// ---------------------------------------------------------------------------
extern "C" void kernel_launch(void* const* d_in, const int* in_sizes, int n_in,
                              void* d_out, int out_size, void* d_ws, size_t ws_size,
                              hipStream_t stream) {
  const float* x   = (const float*)d_in[0];
  const float* wq  = (const float*)d_in[1];
  const float* wk  = (const float*)d_in[2];
  const float* wv  = (const float*)d_in[3];
  const float* lq1 = (const float*)d_in[4];
  const float* lk1 = (const float*)d_in[5];
  const float* lq2 = (const float*)d_in[6];
  const float* lk2 = (const float*)d_in[7];
  float* out = (float*)d_out;

  const size_t MB = 1ull << 20;
  char* ws = (char*)d_ws;
  h16x8*    xhN   = (h16x8*)(ws + 0);          // 16MB  512rb x 32kc
  h16x8*    WpN   = (h16x8*)(ws + 16 * MB);    // 10MB  320nb x 32kc
  h16x8*    qkvN  = (h16x8*)(ws + 26 * MB);    // 64MB  512rb x 128kc (q|k)
  h16x8*    vtN   = (h16x8*)(ws + 90 * MB);    // 16MB  4z x 64db x 64kck
  _Float16* Sbuf  = (_Float16*)(ws + 106 * MB);// 64MB  [att2][z4][2048][2048]
  h16x8*    diffN = (h16x8*)(ws + 170 * MB);   // 32MB  4z x 128rb x 64kc
  _Float16* opre  = (_Float16*)(ws + 202 * MB);// 16MB  8192x1024 row-linear
  float*    lam   = (float*)(ws + 218 * MB);   // 4B

  const float scale = 0.17677669529663689f;  // 1024^-0.25

  cast_xn<<<4096, 256, 0, stream>>>(x, xhN);
  tcwn<<<1024, 256, 0, stream>>>(wq, WpN, 2048, 0, scale);
  tcwn<<<1024, 256, 0, stream>>>(wk, WpN, 2048, 128, 1.0f);
  tcwn<<<512, 256, 0, stream>>>(wv, WpN, 1024, 256, 1.0f);
  lambda_k<<<1, 1024, 0, stream>>>(lq1, lk1, lq2, lk2, lam);

  // qkv = xh @ Wp^T (8192x5120, K=1024) -> q/k native + v^T native
  gemmf<0><<<1280, 256, 0, stream>>>(xhN, WpN, nullptr, qkvN, vtN);

  // S1,S2 = q_p @ k_p^T (fused, 8 batches) -> row-linear f16
  gemmf<1><<<1024, 256, 0, stream>>>(qkvN, qkvN, Sbuf, nullptr, nullptr);

  softmax_diffn<<<512, 256, 0, stream>>>(Sbuf, diffN, lam);

  // opre = diff @ v (K=2048) -> row-linear f16
  gemmf<2><<<256, 256, 0, stream>>>(diffN, vtN, opre, nullptr, nullptr);

  rmsnorm<<<2048, 256, 0, stream>>>(opre, out);
}